// Round 6
// baseline (614.790 us; speedup 1.0000x reference)
//
#include <hip/hip_runtime.h>
#include <hip/hip_bf16.h>

// Shapes fixed by the reference
#define T_TOK 4096
#define I1    512
#define O1    2049
#define O1P   2176        // padded W1 rows (17*128)
#define K1    4608        // 576 groups: 512 spline + 64 silu
#define NG1   576
#define SPLITS1 2
#define KLEN1 2304        // 36 iters per split
#define I2    2049
#define O2    512
#define K2    18560       // 2320 groups: 2049 spline + 271 silu/pad
#define G2    271
#define SPLITS2 12
#define KLEN2 1600        // 25 iters; last split clamps to 15

typedef __attribute__((ext_vector_type(8))) short short8;
typedef __attribute__((ext_vector_type(4))) float floatx4;
typedef __attribute__((address_space(3))) void* lds_ptr_t;
typedef const __attribute__((address_space(1))) void* gmem_ptr_t;

__device__ __forceinline__ unsigned short f2bf(float f) {
  union { __hip_bfloat16 h; unsigned short u; } cv;
  cv.h = __float2bfloat16(f);
  return cv.u;
}
__device__ __forceinline__ unsigned bfr(float f) {          // cheap near-RNE
  union { float f; unsigned u; } c; c.f = f;
  return (c.u + 0x8000u) >> 16;
}
__device__ __forceinline__ float silu_f(float x) { return x / (1.0f + __expf(-x)); }

// All 8 cubic-basis slots for one group as 8 bf16 in a uint4 (branchless funnel shift).
__device__ __forceinline__ uint4 spline_pack(float h) {
  float u = (h + 2.2f) * 2.5f;
  int ji = (int)u;
  ji = ji < 0 ? 0 : (ji > 10 ? 10 : ji);
  float t = u - (float)ji;
  float it = 1.0f - t, t2 = t * t, t3 = t2 * t;
  float b0 = it * it * it * (1.0f / 6.0f);
  float b1 = (3.0f * t3 - 6.0f * t2 + 4.0f) * (1.0f / 6.0f);
  float b2 = (-3.0f * t3 + 3.0f * t2 + 3.0f * t + 1.0f) * (1.0f / 6.0f);
  float b3 = t3 * (1.0f / 6.0f);
  unsigned pk01 = bfr(b0) | (bfr(b1) << 16);
  unsigned pk23 = bfr(b2) | (bfr(b3) << 16);
  unsigned long long p64 = (unsigned long long)pk01 | ((unsigned long long)pk23 << 32);
  bool inR = (h >= -2.2f) && (h < 2.2f);
  p64 = inR ? p64 : 0ull;
  int sh = (ji - 3) * 16;
  int shr = sh < 0 ? -sh : 0;
  int shl = sh < 0 ? 0 : sh;
  __uint128_t v = ((__uint128_t)(p64 >> shr)) << shl;
  union { __uint128_t q; uint4 u4; } cv;
  cv.q = v;
  return cv.u4;
}

// Materialize A1 row-major: A1u[m, g] = uint4 of 8 bf16 (spline g<512, silu g>=512).
// 1 wave per token row; lane-coalesced reads of x and 16B-contiguous stores.
__global__ void pack_a1_kernel(const float* __restrict__ x, uint4* __restrict__ A1u) {
  int wv = threadIdx.x >> 6;                 // 4 waves -> 4 rows/block
  int lane = threadIdx.x & 63;
  int m = blockIdx.x * 4 + wv;
  const float* xr = x + (size_t)m * I1;
  uint4* arow = A1u + (size_t)m * NG1;
#pragma unroll
  for (int i = 0; i < 8; ++i) {              // spline groups g = i*64+lane
    int g = i * 64 + lane;
    arow[g] = spline_pack(xr[g]);
  }
  {                                          // silu group g = 512+lane
    union { unsigned short s[8]; uint4 v; } pk;
    const float4* xq = (const float4*)(xr + lane * 8);
    float4 f0 = xq[0], f1 = xq[1];
    pk.s[0] = f2bf(silu_f(f0.x)); pk.s[1] = f2bf(silu_f(f0.y));
    pk.s[2] = f2bf(silu_f(f0.z)); pk.s[3] = f2bf(silu_f(f0.w));
    pk.s[4] = f2bf(silu_f(f1.x)); pk.s[5] = f2bf(silu_f(f1.y));
    pk.s[6] = f2bf(silu_f(f1.z)); pk.s[7] = f2bf(silu_f(f1.w));
    arow[512 + lane] = pk.v;
  }
}

// SPK[g][m] = uint4 of 8 bf16: silu(St[g*8+c, m]), 0 beyond I. St is (I x M) fp32.
__global__ void silu_pack_kernel(const float* __restrict__ St, uint4* __restrict__ SPK,
                                 int I, int M) {
  int m = blockIdx.x * 256 + threadIdx.x;
  int g = blockIdx.y;
  int off0 = g * 8;
  union { unsigned short s[8]; uint4 v; } pk;
#pragma unroll
  for (int c = 0; c < 8; ++c) {
    int off = off0 + c;
    float v = 0.0f;
    if (off < I) v = silu_f(St[(size_t)off * M + m]);
    pk.s[c] = f2bf(v);
  }
  SPK[(size_t)g * M + m] = pk.v;
}

// W1'[o,k]: k<4096 -> spline_w1[o,k>>3,k&7]*scaler1[o,k>>3]; else base_w1; o>=2049 -> 0
__global__ void pack_w1_kernel(const float* __restrict__ bw, const float* __restrict__ sw,
                               const float* __restrict__ sc, unsigned short* __restrict__ W) {
  int k = blockIdx.x * 256 + threadIdx.x;
  int o = blockIdx.y;                      // < 2176
  float v = 0.0f;
  if (o < O1) {
    if (k < 4096) v = sw[(size_t)o * 4096 + k] * sc[(size_t)o * I1 + (k >> 3)];
    else          v = bw[(size_t)o * I1 + (k - 4096)];
  }
  W[(size_t)o * K1 + k] = f2bf(v);
}

// W2'[o,k]: k<16392 -> spline_w2*scaler2; k<18441 -> base_w2; else 0
__global__ void pack_w2_kernel(const float* __restrict__ bw, const float* __restrict__ sw,
                               const float* __restrict__ sc, unsigned short* __restrict__ W) {
  int k = blockIdx.x * 256 + threadIdx.x;
  if (k >= K2) return;
  int o = blockIdx.y;                      // < 512
  float v = 0.0f;
  if (k < 16392)      v = sw[(size_t)o * 16392 + k] * sc[(size_t)o * I2 + (k >> 3)];
  else if (k < 18441) v = bw[(size_t)o * I2 + (k - 16392)];
  W[(size_t)o * K2 + k] = f2bf(v);
}

// Layer-1 GEMM, pure-DMA (m97 structure): C^T += A @ W1'^T, atomic into zeroed H0t.
// A (4096 x 4608 bf16), W1' (2176 x 4608 bf16). 128x128 tile, BK=64, 4 waves.
// 1-D XCD-swizzled grid: Lb%8 = by&7 (A-row sharers colocated per XCD L2).
__global__ __launch_bounds__(256, 4)
void gemm_dma_kernel(const unsigned short* __restrict__ A,
                     const unsigned short* __restrict__ Bw,
                     float* __restrict__ C)      // C[n*T_TOK + m], pre-zeroed
{
  __shared__ __align__(16) unsigned short As[128 * 64];
  __shared__ __align__(16) unsigned short Bs[128 * 64];

  const int Lb = blockIdx.x;                 // 1088 = 8 * (17 * 4 * 2)
  const int m8 = Lb & 7, r = Lb >> 3;
  const int bx = r % 17;
  const int t  = r / 17;
  const int by = m8 + ((t & 3) << 3);
  const int bz = t >> 2;
  const int ks = bz * KLEN1;

  const int tid = threadIdx.x;
  const int w = tid >> 6, L = tid & 63, q = L >> 4, ln = L & 15;
  const int wm = (w & 1) << 6, wn = (w >> 1) << 6;

  floatx4 zf = {0.f, 0.f, 0.f, 0.f};
  floatx4 acc[4][4];
#pragma unroll
  for (int mt = 0; mt < 4; ++mt)
#pragma unroll
    for (int nt = 0; nt < 4; ++nt) acc[mt][nt] = zf;

  // Staging bases; chunk pattern is r4-invariant (row stride 32, cg identical)
  const int rowS = tid >> 3;                 // 0..31
  const int cg = (tid & 7) ^ (rowS & 7);
  const unsigned short* ga = A  + ((long)by * 128 + rowS) * K1 + ks + cg * 8;
  const unsigned short* gb = Bw + ((long)bx * 128 + rowS) * K1 + ks + cg * 8;
  const int ldsT = tid * 8;

  for (int it = 0; it < KLEN1 / 64; ++it) {
    __syncthreads();
#pragma unroll
    for (int r4 = 0; r4 < 4; ++r4) {
      __builtin_amdgcn_global_load_lds((gmem_ptr_t)(ga + (long)r4 * 32 * K1),
                                       (lds_ptr_t)&As[r4 * 2048 + ldsT], 16, 0, 0);
      __builtin_amdgcn_global_load_lds((gmem_ptr_t)(gb + (long)r4 * 32 * K1),
                                       (lds_ptr_t)&Bs[r4 * 2048 + ldsT], 16, 0, 0);
    }
    ga += 64; gb += 64;
    __syncthreads();
#pragma unroll
    for (int s = 0; s < 2; ++s) {
      short8 af[4], bf[4];
#pragma unroll
      for (int mt = 0; mt < 4; ++mt) {
        int rr = wm + mt * 16 + ln;
        int cl = ((s << 2) | q) ^ (rr & 7);
        af[mt] = *(const short8*)&As[rr * 64 + cl * 8];
      }
#pragma unroll
      for (int nt = 0; nt < 4; ++nt) {
        int rr = wn + nt * 16 + ln;
        int cl = ((s << 2) | q) ^ (rr & 7);
        bf[nt] = *(const short8*)&Bs[rr * 64 + cl * 8];
      }
#pragma unroll
      for (int mt = 0; mt < 4; ++mt)
#pragma unroll
        for (int nt = 0; nt < 4; ++nt)
          acc[mt][nt] = __builtin_amdgcn_mfma_f32_16x16x32_bf16(af[mt], bf[nt], acc[mt][nt], 0, 0, 0);
    }
  }

  // Atomic transposed epilogue: H0t[n, m] += acc  (n = feature, m = token)
#pragma unroll
  for (int mt = 0; mt < 4; ++mt) {
#pragma unroll
    for (int nt = 0; nt < 4; ++nt) {
      int n = bx * 128 + wn + nt * 16 + ln;
      if (n < O1) {
        int m0 = by * 128 + wm + mt * 16 + q * 4;
        float* cp = &C[(size_t)n * T_TOK + m0];
#pragma unroll
        for (int rg = 0; rg < 4; ++rg) atomicAdd(cp + rg, acc[mt][nt][rg]);
      }
    }
  }
}

// Layer-2 fused expand+GEMM, 128x256 tile, 512 threads (8 waves, 2x4), BK=64.
//   St  (I2 x 4096 fp32): transposed H (spline source, lane=m coalesced)
//   SPK (G2 x 4096 uint4): pre-packed silu bf16x8 groups (pad baked in)
//   Bw = W2' (512 x K2 bf16) staged via global_load_lds w16 + XOR chunk swizzle.
// Split-K=12, atomicAdd into pre-zeroed out.
__global__ __launch_bounds__(512, 4)
void kan_gemm256_kernel(const float* __restrict__ St, const uint4* __restrict__ SPK,
                        const unsigned short* __restrict__ Bw, float* __restrict__ C)
{
  __shared__ __align__(16) unsigned short As[128 * 64];
  __shared__ __align__(16) unsigned short Bs[256 * 64];

  const int Lb = blockIdx.x;                 // 768 = 8 * (2 * 4 * 12)
  const int m8 = Lb & 7, r = Lb >> 3;
  const int bx = r & 1;
  const int t  = r >> 1;
  const int by = m8 + ((t & 3) << 3);
  const int bz = t >> 2;
  const int ks = bz * KLEN2;
  int ke = ks + KLEN2; if (ke > K2) ke = K2;

  const int tid = threadIdx.x;
  const int w = tid >> 6, L = tid & 63, q = L >> 4, ln = L & 15;
  const int wm = (w & 1) << 6, wn = (w >> 1) << 6;   // 2 m-waves x 4 n-waves

  // Generator mapping: row = tid&127, 2 groups/thread starting at gh*2 (gh wave-uniform)
  const int row = tid & 127;
  const int gh  = tid >> 7;
  const float* s0  = St  + by * 128 + row;   // + gi*T_TOK
  const uint4* sp0 = SPK + by * 128 + row;   // + (gi-I2)*T_TOK

  floatx4 zf = {0.f, 0.f, 0.f, 0.f};
  floatx4 acc[4][4];
#pragma unroll
  for (int mt = 0; mt < 4; ++mt)
#pragma unroll
    for (int nt = 0; nt < 4; ++nt) acc[mt][nt] = zf;

  // B staging: 4 chunks/thread; r4-invariant pattern (row stride 64, cg identical)
  const int rowB = tid >> 3;                 // 0..63
  const int cgB = (tid & 7) ^ (rowB & 7);
  const unsigned short* gb = Bw + ((long)bx * 256 + rowB) * K2 + ks + cgB * 8;
  const int ldsT = tid * 8;

  uint4 cur[2], nxt[2];
#pragma unroll
  for (int j2 = 0; j2 < 2; ++j2) {           // prologue source load
    int gi = (ks >> 3) + gh * 2 + j2;
    if (gi < I2) cur[j2].x = __float_as_uint(s0[(size_t)gi * T_TOK]);
    else         cur[j2]   = sp0[(size_t)(gi - I2) * T_TOK];
  }

  for (int kc = ks; kc < ke; kc += 64) {
    __syncthreads();
#pragma unroll
    for (int r4 = 0; r4 < 4; ++r4)
      __builtin_amdgcn_global_load_lds((gmem_ptr_t)(gb + (long)r4 * 64 * K2),
                                       (lds_ptr_t)&Bs[r4 * 4096 + ldsT], 16, 0, 0);
    gb += 64;

    if (kc + 64 < ke) {                      // prefetch next iter's sources
#pragma unroll
      for (int j2 = 0; j2 < 2; ++j2) {
        int gi = ((kc + 64) >> 3) + gh * 2 + j2;
        if (gi < I2) nxt[j2].x = __float_as_uint(s0[(size_t)gi * T_TOK]);
        else         nxt[j2]   = sp0[(size_t)(gi - I2) * T_TOK];
      }
    }

    const int gBase = kc >> 3;
#pragma unroll
    for (int j2 = 0; j2 < 2; ++j2) {         // generate A tile from cur
      int g  = gh * 2 + j2;                  // wave-uniform
      int gi = gBase + g;
      int pos = row * 64 + ((g ^ (row & 7)) << 3);
      uint4 val = (gi < I2) ? spline_pack(__uint_as_float(cur[j2].x)) : cur[j2];
      *(uint4*)&As[pos] = val;
    }
    __syncthreads();

#pragma unroll
    for (int s = 0; s < 2; ++s) {
      short8 af[4], bf[4];
#pragma unroll
      for (int mt = 0; mt < 4; ++mt) {
        int rr = wm + mt * 16 + ln;
        int cl = ((s << 2) | q) ^ (rr & 7);
        af[mt] = *(const short8*)&As[rr * 64 + cl * 8];
      }
#pragma unroll
      for (int nt = 0; nt < 4; ++nt) {
        int rr = wn + nt * 16 + ln;          // 0..255
        int cl = ((s << 2) | q) ^ (rr & 7);
        bf[nt] = *(const short8*)&Bs[rr * 64 + cl * 8];
      }
#pragma unroll
      for (int mt = 0; mt < 4; ++mt)
#pragma unroll
        for (int nt = 0; nt < 4; ++nt)
          acc[mt][nt] = __builtin_amdgcn_mfma_f32_16x16x32_bf16(af[mt], bf[nt], acc[mt][nt], 0, 0, 0);
    }
#pragma unroll
    for (int j2 = 0; j2 < 2; ++j2) cur[j2] = nxt[j2];
  }

  // Atomic epilogue: out[m, n] += acc. N=512 exact, no guard.
#pragma unroll
  for (int mt = 0; mt < 4; ++mt) {
#pragma unroll
    for (int nt = 0; nt < 4; ++nt) {
      int n = bx * 256 + wn + nt * 16 + ln;
      int m0 = by * 128 + wm + mt * 16 + q * 4;
#pragma unroll
      for (int rg = 0; rg < 4; ++rg)
        atomicAdd(&C[(size_t)(m0 + rg) * O2 + n], acc[mt][nt][rg]);
    }
  }
}

extern "C" void kernel_launch(void* const* d_in, const int* in_sizes, int n_in,
                              void* d_out, int out_size, void* d_ws, size_t ws_size,
                              hipStream_t stream) {
  const float* x   = (const float*)d_in[0];
  const float* bw1 = (const float*)d_in[1];
  const float* sw1 = (const float*)d_in[2];
  const float* sc1 = (const float*)d_in[3];
  const float* bw2 = (const float*)d_in[4];
  const float* sw2 = (const float*)d_in[5];
  const float* sc2 = (const float*)d_in[6];
  float* out = (float*)d_out;

  // Workspace: A1 | H0t | W1' | W2' | SPK2   (~128.1 MB)
  uint4* A1u = (uint4*)d_ws;                                         // 37.75 MB
  float* H0t = (float*)(A1u + (size_t)T_TOK * NG1);                  // 33.57 MB
  unsigned short* W1 = (unsigned short*)(H0t + (size_t)O1 * T_TOK);  // 20.05 MB
  unsigned short* W2 = W1 + (size_t)O1P * K1;                        // 19.01 MB
  uint4* SPK2 = (uint4*)(W2 + (size_t)O2 * K2);                      // 17.76 MB

  hipMemsetAsync(d_out, 0, (size_t)out_size * sizeof(float), stream);
  hipMemsetAsync(H0t, 0, (size_t)O1 * T_TOK * sizeof(float), stream);

  pack_a1_kernel<<<T_TOK / 4, 256, 0, stream>>>(x, A1u);
  pack_w1_kernel<<<dim3(K1 / 256, O1P), 256, 0, stream>>>(bw1, sw1, sc1, W1);
  pack_w2_kernel<<<dim3((K2 + 255) / 256, O2), 256, 0, stream>>>(bw2, sw2, sc2, W2);

  // Layer 1: H0t(^T) += A1 @ W1'^T. 17*32 blocks x split-K=2 = 1088 blocks.
  gemm_dma_kernel<<<8 * 17 * 4 * SPLITS1, 256, 0, stream>>>(
      (const unsigned short*)A1u, W1, H0t);

  silu_pack_kernel<<<dim3(T_TOK / 256, G2), 256, 0, stream>>>(H0t, SPK2, I2, T_TOK);

  // Layer 2: out += expand(H) @ W2'^T. 2*32 blocks x split-K=12 = 768 blocks.
  kan_gemm256_kernel<<<8 * 2 * 4 * SPLITS2, 512, 0, stream>>>(H0t, SPK2, W2, out);
}

// Round 7
// 575.235 us; speedup vs baseline: 1.0688x; 1.0688x over previous
//
#include <hip/hip_runtime.h>
#include <hip/hip_bf16.h>

// Shapes fixed by the reference
#define T_TOK 4096
#define I1    512
#define O1    2049
#define O1P   2176        // padded W1 rows (17*128)
#define K1    4608        // 576 groups: 512 spline + 64 silu
#define G1    64
#define I2    2049
#define O2    512
#define K2    18560       // 2320 groups: 2049 spline + 271 silu/pad
#define G2    271
#define SPLITS2 8
#define KLEN2 2368        // 37 iters; last slice 31

typedef __attribute__((ext_vector_type(8))) short short8;
typedef __attribute__((ext_vector_type(4))) float floatx4;
typedef __attribute__((address_space(3))) void* lds_ptr_t;
typedef const __attribute__((address_space(1))) void* gmem_ptr_t;

__device__ __forceinline__ unsigned short f2bf(float f) {
  union { __hip_bfloat16 h; unsigned short u; } cv;
  cv.h = __float2bfloat16(f);
  return cv.u;
}
__device__ __forceinline__ unsigned bfr(float f) {          // cheap near-RNE
  union { float f; unsigned u; } c; c.f = f;
  return (c.u + 0x8000u) >> 16;
}
__device__ __forceinline__ float silu_f(float x) { return x / (1.0f + __expf(-x)); }

// All 8 cubic-basis slots for one group as 8 bf16 in a uint4 (branchless funnel shift).
__device__ __forceinline__ uint4 spline_pack(float h) {
  float u = (h + 2.2f) * 2.5f;
  int ji = (int)u;
  ji = ji < 0 ? 0 : (ji > 10 ? 10 : ji);
  float t = u - (float)ji;
  float it = 1.0f - t, t2 = t * t, t3 = t2 * t;
  float b0 = it * it * it * (1.0f / 6.0f);
  float b1 = (3.0f * t3 - 6.0f * t2 + 4.0f) * (1.0f / 6.0f);
  float b2 = (-3.0f * t3 + 3.0f * t2 + 3.0f * t + 1.0f) * (1.0f / 6.0f);
  float b3 = t3 * (1.0f / 6.0f);
  unsigned pk01 = bfr(b0) | (bfr(b1) << 16);
  unsigned pk23 = bfr(b2) | (bfr(b3) << 16);
  unsigned long long p64 = (unsigned long long)pk01 | ((unsigned long long)pk23 << 32);
  bool inR = (h >= -2.2f) && (h < 2.2f);
  p64 = inR ? p64 : 0ull;
  int sh = (ji - 3) * 16;
  int shr = sh < 0 ? -sh : 0;
  int shl = sh < 0 ? 0 : sh;
  __uint128_t v = ((__uint128_t)(p64 >> shr)) << shl;
  union { __uint128_t q; uint4 u4; } cv;
  cv.q = v;
  return cv.u4;
}

// 32x32 LDS-tiled transpose: src (R x C) -> dst (C x R). R,C multiples of 32.
__global__ void transpose_kernel(const float* __restrict__ src, float* __restrict__ dst,
                                 int R, int C) {
  __shared__ float t[32][33];
  int c0 = blockIdx.x * 32, r0 = blockIdx.y * 32;
  int tx = threadIdx.x & 31, ty = threadIdx.x >> 5;   // 32 x 8
#pragma unroll
  for (int i = 0; i < 32; i += 8)
    t[ty + i][tx] = src[(size_t)(r0 + ty + i) * C + c0 + tx];
  __syncthreads();
#pragma unroll
  for (int i = 0; i < 32; i += 8)
    dst[(size_t)(c0 + ty + i) * R + r0 + tx] = t[tx][ty + i];
}

// SPK[g][m] = uint4 of 8 bf16: silu(St[g*8+c, m]), 0 beyond I. St is (I x M) fp32.
__global__ void silu_pack_kernel(const float* __restrict__ St, uint4* __restrict__ SPK,
                                 int I, int M) {
  int m = blockIdx.x * 256 + threadIdx.x;
  int g = blockIdx.y;
  int off0 = g * 8;
  union { unsigned short s[8]; uint4 v; } pk;
#pragma unroll
  for (int c = 0; c < 8; ++c) {
    int off = off0 + c;
    float v = 0.0f;
    if (off < I) v = silu_f(St[(size_t)off * M + m]);
    pk.s[c] = f2bf(v);
  }
  SPK[(size_t)g * M + m] = pk.v;
}

// W1'[o,k]: k<4096 -> spline_w1[o,k>>3,k&7]*scaler1[o,k>>3]; else base_w1; o>=2049 -> 0
__global__ void pack_w1_kernel(const float* __restrict__ bw, const float* __restrict__ sw,
                               const float* __restrict__ sc, unsigned short* __restrict__ W) {
  int k = blockIdx.x * 256 + threadIdx.x;
  int o = blockIdx.y;                      // < 2176
  float v = 0.0f;
  if (o < O1) {
    if (k < 4096) v = sw[(size_t)o * 4096 + k] * sc[(size_t)o * I1 + (k >> 3)];
    else          v = bw[(size_t)o * I1 + (k - 4096)];
  }
  W[(size_t)o * K1 + k] = f2bf(v);
}

// W2'[o,k]: k<16392 -> spline_w2*scaler2; k<18441 -> base_w2; else 0
__global__ void pack_w2_kernel(const float* __restrict__ bw, const float* __restrict__ sw,
                               const float* __restrict__ sc, unsigned short* __restrict__ W) {
  int k = blockIdx.x * 256 + threadIdx.x;
  if (k >= K2) return;
  int o = blockIdx.y;                      // < 512
  float v = 0.0f;
  if (k < 16392)      v = sw[(size_t)o * 16392 + k] * sc[(size_t)o * I2 + (k >> 3)];
  else if (k < 18441) v = bw[(size_t)o * I2 + (k - 16392)];
  W[(size_t)o * K2 + k] = f2bf(v);
}

// Fused KAN-expand + GEMM, SINGLE-BARRIER DOUBLE-BUFFERED K-loop.
// Per iter i (c=i&1):  __syncthreads()  [drains B-DMA issued a full iter ago +
// prior gen's lgkm; protects buffers 1-c from last iter's readers]  ->
// issue B-DMA_{i+1} into Bs[1-c]; gen A_{i+1} into As[1-c] (src prefetched);
// -> MFMA on As[c]/Bs[c].  Issue->drain distance = gen+MFMA (vs ~0 in the
// 2-barrier m97 shape), so the vmcnt(0) drain at the barrier is cheap.
//   St (I x M fp32): spline source, lane=m coalesced.  SPK (G x M uint4):
//   pre-packed silu bf16x8 groups.  Bw (Nrows x Ktot bf16): DMA w16 + XOR swizzle.
// storeMode 1: plain float4 C[n*ldc+m] (transposed, layer 1).
// storeMode 2: atomicAdd C[m*ldc+n] (layer 2 split-K, C pre-zeroed, small C).
__global__ __launch_bounds__(256, 2)
void kan_gemm_db_kernel(const float* __restrict__ St, const uint4* __restrict__ SPK,
                        const unsigned short* __restrict__ Bw, float* __restrict__ C,
                        int I, int Ktot, int M, int N, int ldc, int kLen,
                        int nBx, int storeMode)
{
  __shared__ __align__(16) unsigned short As[2][128 * 64];
  __shared__ __align__(16) unsigned short Bs[2][128 * 64];

  // XCD-swizzled decode: Lb%8 pins by&7 -> source-row sharers colocated per XCD.
  const int Lb = blockIdx.x;
  const int m8 = Lb & 7, r = Lb >> 3;
  const int bx = r % nBx;
  const int t  = r / nBx;
  const int by = m8 + ((t & 3) << 3);
  const int bz = t >> 2;
  const int ks = bz * kLen;
  int ke = ks + kLen; if (ke > Ktot) ke = Ktot;
  const int nIter = (ke - ks) >> 6;

  const int tid = threadIdx.x;
  const int w = tid >> 6, L = tid & 63, q = L >> 4, ln = L & 15;
  const int wm = (w & 1) << 6, wn = (w >> 1) << 6;

  // Generator mapping: row = tid&127, 4 groups starting at gh*4 (gh wave-uniform)
  const int row = tid & 127;
  const int gh  = tid >> 7;
  const float* s0  = St  + by * 128 + row;   // + gi*M
  const uint4* sp0 = SPK + by * 128 + row;   // + (gi-I)*M

  floatx4 zf = {0.f, 0.f, 0.f, 0.f};
  floatx4 acc[4][4];
#pragma unroll
  for (int mt = 0; mt < 4; ++mt)
#pragma unroll
    for (int nt = 0; nt < 4; ++nt) acc[mt][nt] = zf;

  // B staging: 4 chunks/thread; r4-invariant pattern (row stride 32, same cg)
  const int rowB = tid >> 3;                 // 0..31
  const int cgB = (tid & 7) ^ (rowB & 7);
  const unsigned short* gb0 = Bw + ((long)bx * 128 + rowB) * (long)Ktot + ks + cgB * 8;
  const int ldsT = tid * 8;

  uint4 cur[4];
  // ---- prologue: src chunk0 -> gen As[0]; B chunk0 -> Bs[0]; preload src chunk1
  {
    int gBase = (ks >> 3) + gh * 4;
#pragma unroll
    for (int j = 0; j < 4; ++j) {
      int gi = gBase + j;
      if (gi < I) cur[j].x = __float_as_uint(s0[(size_t)gi * M]);
      else        cur[j]   = sp0[(size_t)(gi - I) * M];
    }
#pragma unroll
    for (int r4 = 0; r4 < 4; ++r4)
      __builtin_amdgcn_global_load_lds((gmem_ptr_t)(gb0 + (long)r4 * 32 * Ktot),
                                       (lds_ptr_t)&Bs[0][r4 * 2048 + ldsT], 16, 0, 0);
#pragma unroll
    for (int j = 0; j < 4; ++j) {
      int g = gh * 4 + j;
      int gi = gBase + j;
      int pos = row * 64 + ((g ^ (row & 7)) << 3);
      uint4 val = (gi < I) ? spline_pack(__uint_as_float(cur[j].x)) : cur[j];
      *(uint4*)&As[0][pos] = val;
    }
    if (nIter > 1) {                          // src for iter 1
      int gB1 = ((ks + 64) >> 3) + gh * 4;
#pragma unroll
      for (int j = 0; j < 4; ++j) {
        int gi = gB1 + j;
        if (gi < I) cur[j].x = __float_as_uint(s0[(size_t)gi * M]);
        else        cur[j]   = sp0[(size_t)(gi - I) * M];
      }
    }
  }

  for (int i = 0; i < nIter; ++i) {
    const int c = i & 1;
    __syncthreads();                          // cheap drain: DMA_i issued 1 iter ago
    if (i + 1 < nIter) {
      const unsigned short* g = gb0 + (long)(i + 1) * 64;
#pragma unroll
      for (int r4 = 0; r4 < 4; ++r4)          // B-DMA for i+1
        __builtin_amdgcn_global_load_lds((gmem_ptr_t)(g + (long)r4 * 32 * Ktot),
                                         (lds_ptr_t)&Bs[1 - c][r4 * 2048 + ldsT], 16, 0, 0);
      int gBase = ((ks + (i + 1) * 64) >> 3) + gh * 4;
#pragma unroll
      for (int j = 0; j < 4; ++j) {           // gen A for i+1 from prefetched cur
        int g2 = gh * 4 + j;
        int gi = gBase + j;
        int pos = row * 64 + ((g2 ^ (row & 7)) << 3);
        uint4 val = (gi < I) ? spline_pack(__uint_as_float(cur[j].x)) : cur[j];
        *(uint4*)&As[1 - c][pos] = val;
      }
      if (i + 2 < nIter) {                    // prefetch src for i+2
        int gB2 = ((ks + (i + 2) * 64) >> 3) + gh * 4;
#pragma unroll
        for (int j = 0; j < 4; ++j) {
          int gi = gB2 + j;
          if (gi < I) cur[j].x = __float_as_uint(s0[(size_t)gi * M]);
          else        cur[j]   = sp0[(size_t)(gi - I) * M];
        }
      }
    }

#pragma unroll
    for (int s = 0; s < 2; ++s) {
      short8 af[4], bf[4];
#pragma unroll
      for (int mt = 0; mt < 4; ++mt) {
        int rr = wm + mt * 16 + ln;
        int cl = ((s << 2) | q) ^ (rr & 7);
        af[mt] = *(const short8*)&As[c][rr * 64 + cl * 8];
      }
#pragma unroll
      for (int nt = 0; nt < 4; ++nt) {
        int rr = wn + nt * 16 + ln;
        int cl = ((s << 2) | q) ^ (rr & 7);
        bf[nt] = *(const short8*)&Bs[c][rr * 64 + cl * 8];
      }
#pragma unroll
      for (int mt = 0; mt < 4; ++mt)
#pragma unroll
        for (int nt = 0; nt < 4; ++nt)
          acc[mt][nt] = __builtin_amdgcn_mfma_f32_16x16x32_bf16(af[mt], bf[nt], acc[mt][nt], 0, 0, 0);
    }
  }

  // Epilogue. D layout: col = lane&15 (n), row = q*4+reg (m)  [m89-verified]
  if (storeMode == 1) {                       // plain transposed float4 (layer 1)
#pragma unroll
    for (int mt = 0; mt < 4; ++mt) {
#pragma unroll
      for (int nt = 0; nt < 4; ++nt) {
        int n = bx * 128 + wn + nt * 16 + ln;
        if (n < N) {
          int m0 = by * 128 + wm + mt * 16 + q * 4;
          *(float4*)&C[(size_t)n * ldc + m0] = *(float4*)&acc[mt][nt];
        }
      }
    }
  } else {                                    // atomic accumulate (layer 2 split-K)
#pragma unroll
    for (int mt = 0; mt < 4; ++mt) {
#pragma unroll
      for (int nt = 0; nt < 4; ++nt) {
        int n = bx * 128 + wn + nt * 16 + ln;
        if (n < N) {
          int m0 = by * 128 + wm + mt * 16 + q * 4;
#pragma unroll
          for (int rg = 0; rg < 4; ++rg)
            atomicAdd(&C[(size_t)(m0 + rg) * ldc + n], acc[mt][nt][rg]);
        }
      }
    }
  }
}

extern "C" void kernel_launch(void* const* d_in, const int* in_sizes, int n_in,
                              void* d_out, int out_size, void* d_ws, size_t ws_size,
                              hipStream_t stream) {
  const float* x   = (const float*)d_in[0];
  const float* bw1 = (const float*)d_in[1];
  const float* sw1 = (const float*)d_in[2];
  const float* sc1 = (const float*)d_in[3];
  const float* bw2 = (const float*)d_in[4];
  const float* sw2 = (const float*)d_in[5];
  const float* sc2 = (const float*)d_in[6];
  float* out = (float*)d_out;

  // Workspace: Xt | H0t | W1' | W2' | SPK1 | SPK2   (~103 MB)
  float* Xt  = (float*)d_ws;                                         //  8.39 MB
  float* H0t = Xt + (size_t)I1 * T_TOK;                              // 33.57 MB
  unsigned short* W1 = (unsigned short*)(H0t + (size_t)O1 * T_TOK);  // 20.05 MB
  unsigned short* W2 = W1 + (size_t)O1P * K1;                        // 19.01 MB
  uint4* SPK1 = (uint4*)(W2 + (size_t)O2 * K2);                      //  4.19 MB
  uint4* SPK2 = SPK1 + (size_t)G1 * T_TOK;                           // 17.76 MB

  hipMemsetAsync(d_out, 0, (size_t)out_size * sizeof(float), stream);

  transpose_kernel<<<dim3(I1 / 32, T_TOK / 32), 256, 0, stream>>>(x, Xt, T_TOK, I1);
  pack_w1_kernel<<<dim3(K1 / 256, O1P), 256, 0, stream>>>(bw1, sw1, sc1, W1);
  pack_w2_kernel<<<dim3((K2 + 255) / 256, O2), 256, 0, stream>>>(bw2, sw2, sc2, W2);
  silu_pack_kernel<<<dim3(T_TOK / 256, G1), 256, 0, stream>>>(Xt, SPK1, I1, T_TOK);

  // Layer 1: H0t(^T) = expand(x) @ W1'^T. 544 blocks, full-K, plain stores.
  kan_gemm_db_kernel<<<8 * 17 * 4, 256, 0, stream>>>(
      Xt, SPK1, W1, H0t, I1, K1, T_TOK, O1, T_TOK, K1, 17, 1);

  silu_pack_kernel<<<dim3(T_TOK / 256, G2), 256, 0, stream>>>(H0t, SPK2, I2, T_TOK);

  // Layer 2: out += expand(H) @ W2'^T. 4 bx x 32 by x split-K=8 = 1024 blocks.
  kan_gemm_db_kernel<<<8 * 4 * 4 * SPLITS2, 256, 0, stream>>>(
      H0t, SPK2, W2, out, I2, K2, T_TOK, O2, O2, KLEN2, 4, 2);
}

// Round 8
// 507.059 us; speedup vs baseline: 1.2125x; 1.1345x over previous
//
#include <hip/hip_runtime.h>
#include <hip/hip_bf16.h>

// Shapes fixed by the reference
#define T_TOK 4096
#define I1    512
#define O1    2049
#define O1P   2176        // padded W1 rows (17*128)
#define K1    4608        // 576 groups: 512 spline + 64 silu
#define G1    64
#define I2    2049
#define O2    512
#define K2    18560       // 2320 groups: 2049 spline + 271 silu/pad
#define G2    271
#define SPLITS2 8
#define KLEN2 2368        // 37 iters; last slice 31

typedef __attribute__((ext_vector_type(8))) short short8;
typedef __attribute__((ext_vector_type(4))) float floatx4;
typedef __attribute__((address_space(3))) void* lds_ptr_t;
typedef const __attribute__((address_space(1))) void* gmem_ptr_t;

__device__ __forceinline__ unsigned short f2bf(float f) {
  union { __hip_bfloat16 h; unsigned short u; } cv;
  cv.h = __float2bfloat16(f);
  return cv.u;
}
__device__ __forceinline__ unsigned bfr(float f) {          // cheap near-RNE
  union { float f; unsigned u; } c; c.f = f;
  return (c.u + 0x8000u) >> 16;
}
__device__ __forceinline__ float silu_f(float x) { return x / (1.0f + __expf(-x)); }

// All 8 cubic-basis slots for one group as 8 bf16 in a uint4 (branchless funnel shift).
__device__ __forceinline__ uint4 spline_pack(float h) {
  float u = (h + 2.2f) * 2.5f;
  int ji = (int)u;
  ji = ji < 0 ? 0 : (ji > 10 ? 10 : ji);
  float t = u - (float)ji;
  float it = 1.0f - t, t2 = t * t, t3 = t2 * t;
  float b0 = it * it * it * (1.0f / 6.0f);
  float b1 = (3.0f * t3 - 6.0f * t2 + 4.0f) * (1.0f / 6.0f);
  float b2 = (-3.0f * t3 + 3.0f * t2 + 3.0f * t + 1.0f) * (1.0f / 6.0f);
  float b3 = t3 * (1.0f / 6.0f);
  unsigned pk01 = bfr(b0) | (bfr(b1) << 16);
  unsigned pk23 = bfr(b2) | (bfr(b3) << 16);
  unsigned long long p64 = (unsigned long long)pk01 | ((unsigned long long)pk23 << 32);
  bool inR = (h >= -2.2f) && (h < 2.2f);
  p64 = inR ? p64 : 0ull;
  int sh = (ji - 3) * 16;
  int shr = sh < 0 ? -sh : 0;
  int shl = sh < 0 ? 0 : sh;
  __uint128_t v = ((__uint128_t)(p64 >> shr)) << shl;
  union { __uint128_t q; uint4 u4; } cv;
  cv.q = v;
  return cv.u4;
}

// 32x32 LDS-tiled transpose: src (R x C) -> dst (C x R). R,C multiples of 32.
__global__ void transpose_kernel(const float* __restrict__ src, float* __restrict__ dst,
                                 int R, int C) {
  __shared__ float t[32][33];
  int c0 = blockIdx.x * 32, r0 = blockIdx.y * 32;
  int tx = threadIdx.x & 31, ty = threadIdx.x >> 5;   // 32 x 8
#pragma unroll
  for (int i = 0; i < 32; i += 8)
    t[ty + i][tx] = src[(size_t)(r0 + ty + i) * C + c0 + tx];
  __syncthreads();
#pragma unroll
  for (int i = 0; i < 32; i += 8)
    dst[(size_t)(c0 + ty + i) * R + r0 + tx] = t[tx][ty + i];
}

// SPK[g][m] = uint4 of 8 bf16: silu(St[g*8+c, m]), 0 beyond I. St is (I x M) fp32.
__global__ void silu_pack_kernel(const float* __restrict__ St, uint4* __restrict__ SPK,
                                 int I, int M) {
  int m = blockIdx.x * 256 + threadIdx.x;
  int g = blockIdx.y;
  int off0 = g * 8;
  union { unsigned short s[8]; uint4 v; } pk;
#pragma unroll
  for (int c = 0; c < 8; ++c) {
    int off = off0 + c;
    float v = 0.0f;
    if (off < I) v = silu_f(St[(size_t)off * M + m]);
    pk.s[c] = f2bf(v);
  }
  SPK[(size_t)g * M + m] = pk.v;
}

// W1'[o,k]: k<4096 -> spline_w1[o,k>>3,k&7]*scaler1[o,k>>3]; else base_w1; o>=2049 -> 0
__global__ void pack_w1_kernel(const float* __restrict__ bw, const float* __restrict__ sw,
                               const float* __restrict__ sc, unsigned short* __restrict__ W) {
  int k = blockIdx.x * 256 + threadIdx.x;
  int o = blockIdx.y;                      // < 2176
  float v = 0.0f;
  if (o < O1) {
    if (k < 4096) v = sw[(size_t)o * 4096 + k] * sc[(size_t)o * I1 + (k >> 3)];
    else          v = bw[(size_t)o * I1 + (k - 4096)];
  }
  W[(size_t)o * K1 + k] = f2bf(v);
}

// W2'[o,k]: k<16392 -> spline_w2*scaler2; k<18441 -> base_w2; else 0
__global__ void pack_w2_kernel(const float* __restrict__ bw, const float* __restrict__ sw,
                               const float* __restrict__ sc, unsigned short* __restrict__ W) {
  int k = blockIdx.x * 256 + threadIdx.x;
  if (k >= K2) return;
  int o = blockIdx.y;                      // < 512
  float v = 0.0f;
  if (k < 16392)      v = sw[(size_t)o * 16392 + k] * sc[(size_t)o * I2 + (k >> 3)];
  else if (k < 18441) v = bw[(size_t)o * I2 + (k - 16392)];
  W[(size_t)o * K2 + k] = f2bf(v);
}

// Fused KAN-expand + GEMM (R4 structure: 32 KB LDS, 2-barrier, 1-iter src prefetch).
//   St (I x M fp32): spline source, lane=m coalesced. SPK (G x M uint4): pre-packed
//   silu bf16x8. Bw (Nrows x Ktot bf16): global_load_lds w16 + XOR chunk swizzle.
// Grid decode (B-affinity XCD swizzle): Lb%8 together with idx>>5 forms the
// B-group id g2=(bx,bz); all 32 by-siblings of a group share Lb%8 -> same XCD
// (blockIdx%8 round-robin heuristic), so the shared B-stream stays XCD-L2-resident
// (~200cyc) instead of HBM (~900cyc). Per-XCD B footprint: <=4 groups * <=1.2MB < 4MB.
// storeMode 1: plain float4 C[n*ldc+m] (transposed, layer 1).
// storeMode 2: atomicAdd C[m*ldc+n] (layer 2 split-K, C pre-zeroed, small C).
__global__ __launch_bounds__(256, 4)
void kan_gemm_kernel(const float* __restrict__ St, const uint4* __restrict__ SPK,
                     const unsigned short* __restrict__ Bw, float* __restrict__ C,
                     int I, int Ktot, int M, int N, int ldc, int kLen,
                     int nBx, int nGrp, int storeMode)
{
  __shared__ __align__(16) unsigned short As[128 * 64];
  __shared__ __align__(16) unsigned short Bs[128 * 64];

  // B-affinity decode
  const int m8  = blockIdx.x & 7;
  const int idx = blockIdx.x >> 3;
  const int by  = idx & 31;                 // T_TOK/128 = 32 M-blocks
  const int g2  = ((idx >> 5) << 3) + m8;   // B-group id
  if (g2 >= nGrp) return;                   // hole blocks (L1: 224 of 768)
  const int bx = g2 % nBx;
  const int bz = g2 / nBx;

  const int ks = bz * kLen;
  int ke = ks + kLen; if (ke > Ktot) ke = Ktot;

  const int tid = threadIdx.x;
  const int w = tid >> 6, L = tid & 63, q = L >> 4, ln = L & 15;
  const int wm = (w & 1) << 6, wn = (w >> 1) << 6;

  // Generator mapping: thread -> (m-row = tid&127, 4 groups starting at gh*4)
  const int row = tid & 127;
  const int gh  = tid >> 7;                 // wave-uniform
  const float* s0  = St  + by * 128 + row;  // + gi*M -> feature gi, lane=m coalesced
  const uint4* sp0 = SPK + by * 128 + row;  // + (gi-I)*M

  floatx4 zf = {0.f, 0.f, 0.f, 0.f};
  floatx4 acc[4][4];
#pragma unroll
  for (int mt = 0; mt < 4; ++mt)
#pragma unroll
    for (int nt = 0; nt < 4; ++nt) acc[mt][nt] = zf;

  // B staging: 4 chunks/thread; r4-invariant pattern (row stride 32, same cg)
  const int rowB = tid >> 3;                // 0..31
  const int cgB = (tid & 7) ^ (rowB & 7);
  const unsigned short* gb = Bw + ((long)bx * 128 + rowB) * (long)Ktot + ks + cgB * 8;
  const int ldsT = tid * 8;

  // --- source prefetch: cur = iter kc, nxt = iter kc+64 ---
  uint4 cur[4], nxt[4];
#pragma unroll
  for (int j2 = 0; j2 < 4; ++j2) {          // prologue load (iter 0)
    int gi = (ks >> 3) + gh * 4 + j2;
    if (gi < I) cur[j2].x = __float_as_uint(s0[(size_t)gi * M]);
    else        cur[j2]   = sp0[(size_t)(gi - I) * M];
  }

  for (int kc = ks; kc < ke; kc += 64) {
    __syncthreads();                        // prior MFMA done reading LDS
#pragma unroll
    for (int r4 = 0; r4 < 4; ++r4)          // B DMA: in flight during generation
      __builtin_amdgcn_global_load_lds((gmem_ptr_t)(gb + (long)r4 * 32 * Ktot),
                                       (lds_ptr_t)&Bs[r4 * 2048 + ldsT], 16, 0, 0);
    gb += 64;

    if (kc + 64 < ke) {                     // issue next iter's source loads NOW
#pragma unroll
      for (int j2 = 0; j2 < 4; ++j2) {
        int gi = ((kc + 64) >> 3) + gh * 4 + j2;
        if (gi < I) nxt[j2].x = __float_as_uint(s0[(size_t)gi * M]);
        else        nxt[j2]   = sp0[(size_t)(gi - I) * M];
      }
    }

    const int gBase = (kc >> 3) + gh * 4;
#pragma unroll
    for (int j2 = 0; j2 < 4; ++j2) {        // generate A tile from cur
      int g  = gh * 4 + j2;                 // local group 0..7 (wave-uniform)
      int gi = gBase + j2;
      int pos = row * 64 + ((g ^ (row & 7)) << 3);
      uint4 val = (gi < I) ? spline_pack(__uint_as_float(cur[j2].x)) : cur[j2];
      *(uint4*)&As[pos] = val;              // one ds_write_b128, swizzle-spread
    }
    __syncthreads();                        // A generated + B DMA (+ nxt loads) drained

#pragma unroll
    for (int s = 0; s < 2; ++s) {
      short8 af[4], bf[4];
#pragma unroll
      for (int mt = 0; mt < 4; ++mt) {
        int rr = wm + mt * 16 + ln;
        int cl = ((s << 2) | q) ^ (rr & 7);
        af[mt] = *(const short8*)&As[rr * 64 + cl * 8];
      }
#pragma unroll
      for (int nt = 0; nt < 4; ++nt) {
        int rr = wn + nt * 16 + ln;
        int cl = ((s << 2) | q) ^ (rr & 7);
        bf[nt] = *(const short8*)&Bs[rr * 64 + cl * 8];
      }
#pragma unroll
      for (int mt = 0; mt < 4; ++mt)
#pragma unroll
        for (int nt = 0; nt < 4; ++nt)
          acc[mt][nt] = __builtin_amdgcn_mfma_f32_16x16x32_bf16(af[mt], bf[nt], acc[mt][nt], 0, 0, 0);
    }
#pragma unroll
    for (int j2 = 0; j2 < 4; ++j2) cur[j2] = nxt[j2];
  }

  // Epilogue. D layout: col = lane&15 (n), row = q*4+reg (m)  [m89-verified]
  if (storeMode == 1) {                     // transposed float4 store (layer 1 -> H^T)
#pragma unroll
    for (int mt = 0; mt < 4; ++mt) {
#pragma unroll
      for (int nt = 0; nt < 4; ++nt) {
        int n = bx * 128 + wn + nt * 16 + ln;
        if (n < N) {
          int m0 = by * 128 + wm + mt * 16 + q * 4;
          *(float4*)&C[(size_t)n * ldc + m0] = *(float4*)&acc[mt][nt];
        }
      }
    }
  } else {                                  // atomic accumulate (layer 2, split-K)
#pragma unroll
    for (int mt = 0; mt < 4; ++mt) {
#pragma unroll
      for (int nt = 0; nt < 4; ++nt) {
        int n = bx * 128 + wn + nt * 16 + ln;
        if (n < N) {
          int m0 = by * 128 + wm + mt * 16 + q * 4;
#pragma unroll
          for (int rg = 0; rg < 4; ++rg)
            atomicAdd(&C[(size_t)(m0 + rg) * ldc + n], acc[mt][nt][rg]);
        }
      }
    }
  }
}

extern "C" void kernel_launch(void* const* d_in, const int* in_sizes, int n_in,
                              void* d_out, int out_size, void* d_ws, size_t ws_size,
                              hipStream_t stream) {
  const float* x   = (const float*)d_in[0];
  const float* bw1 = (const float*)d_in[1];
  const float* sw1 = (const float*)d_in[2];
  const float* sc1 = (const float*)d_in[3];
  const float* bw2 = (const float*)d_in[4];
  const float* sw2 = (const float*)d_in[5];
  const float* sc2 = (const float*)d_in[6];
  float* out = (float*)d_out;

  // Workspace: Xt | H0t | W1' | W2' | SPK1 | SPK2   (~103 MB)
  float* Xt  = (float*)d_ws;                                         //  8.39 MB
  float* H0t = Xt + (size_t)I1 * T_TOK;                              // 33.57 MB
  unsigned short* W1 = (unsigned short*)(H0t + (size_t)O1 * T_TOK);  // 20.05 MB
  unsigned short* W2 = W1 + (size_t)O1P * K1;                        // 19.01 MB
  uint4* SPK1 = (uint4*)(W2 + (size_t)O2 * K2);                      //  4.19 MB
  uint4* SPK2 = SPK1 + (size_t)G1 * T_TOK;                           // 17.76 MB

  hipMemsetAsync(d_out, 0, (size_t)out_size * sizeof(float), stream);

  transpose_kernel<<<dim3(I1 / 32, T_TOK / 32), 256, 0, stream>>>(x, Xt, T_TOK, I1);
  pack_w1_kernel<<<dim3(K1 / 256, O1P), 256, 0, stream>>>(bw1, sw1, sc1, W1);
  pack_w2_kernel<<<dim3((K2 + 255) / 256, O2), 256, 0, stream>>>(bw2, sw2, sc2, W2);
  silu_pack_kernel<<<dim3(T_TOK / 256, G1), 256, 0, stream>>>(Xt, SPK1, I1, T_TOK);

  // Layer 1: H0t(^T) = expand(x) @ W1'^T. nGrp=17 B-groups, full-K.
  // Grid 768 = 8 XCD-slots * 32 by * ceil(17/8); 224 hole blocks exit at decode.
  kan_gemm_kernel<<<8 * 32 * 3, 256, 0, stream>>>(
      Xt, SPK1, W1, H0t, I1, K1, T_TOK, O1, T_TOK, K1, 17, 17, 1);

  silu_pack_kernel<<<dim3(T_TOK / 256, G2), 256, 0, stream>>>(H0t, SPK2, I2, T_TOK);

  // Layer 2: out += expand(H) @ W2'^T. nGrp=32 (4 bx * 8 K-splits) -> grid 1024.
  kan_gemm_kernel<<<8 * 32 * 4, 256, 0, stream>>>(
      H0t, SPK2, W2, out, I2, K2, T_TOK, O2, O2, KLEN2, 4, 32, 2);
}